// Round 1
// baseline (332.520 us; speedup 1.0000x reference)
//
#include <hip/hip_runtime.h>

// CapsuleOut: B=256, O=10, R=1152, I=8, D=16, 3 routing iterations.
// One block per (b,o). 384 threads, 3 routes/thread, priors kept in registers.

#define BB 256
#define OO 10
#define RR 1152
#define II 8
#define DD 16
#define NITER 3
#define NTHREADS 384
#define RPT 3
#define NWAVES 6

__global__ __launch_bounds__(NTHREADS) void capsule_kernel(
    const float* __restrict__ inp,   // [B,R,I]
    const float* __restrict__ W,     // [O,R,I,D]
    float* __restrict__ out)         // [B,O,D]
{
    const int bid = blockIdx.x;
    const int o = bid / BB;          // 256 consecutive blocks share one W[o] slice
    const int b = bid % BB;
    const int tid = threadIdx.x;
    const int lane = tid & 63;
    const int wid = tid >> 6;

    __shared__ float red_m[NWAVES];
    __shared__ float red_s[NWAVES * 17];

    float pri[RPT][DD];
    float logit[RPT];

    // ---- priors: pri[k][d] = sum_i inp[b, r, i] * W[o, r, i, d] ----
    #pragma unroll
    for (int k = 0; k < RPT; ++k) {
        const int r = tid + k * NTHREADS;
        const float4* wrow = reinterpret_cast<const float4*>(
            W + ((size_t)o * RR + r) * (II * DD));          // 128 floats, 16B aligned
        const float4* irow = reinterpret_cast<const float4*>(
            inp + ((size_t)b * RR + r) * II);               // 8 floats, 32B aligned
        const float4 ia = irow[0];
        const float4 ib = irow[1];
        const float in8[8] = {ia.x, ia.y, ia.z, ia.w, ib.x, ib.y, ib.z, ib.w};
        float4 a0 = make_float4(0.f, 0.f, 0.f, 0.f);
        float4 a1 = a0, a2 = a0, a3 = a0;
        #pragma unroll
        for (int i = 0; i < II; ++i) {
            const float s = in8[i];
            const float4 w0 = wrow[i * 4 + 0];
            const float4 w1 = wrow[i * 4 + 1];
            const float4 w2 = wrow[i * 4 + 2];
            const float4 w3 = wrow[i * 4 + 3];
            a0.x = fmaf(s, w0.x, a0.x); a0.y = fmaf(s, w0.y, a0.y);
            a0.z = fmaf(s, w0.z, a0.z); a0.w = fmaf(s, w0.w, a0.w);
            a1.x = fmaf(s, w1.x, a1.x); a1.y = fmaf(s, w1.y, a1.y);
            a1.z = fmaf(s, w1.z, a1.z); a1.w = fmaf(s, w1.w, a1.w);
            a2.x = fmaf(s, w2.x, a2.x); a2.y = fmaf(s, w2.y, a2.y);
            a2.z = fmaf(s, w2.z, a2.z); a2.w = fmaf(s, w2.w, a2.w);
            a3.x = fmaf(s, w3.x, a3.x); a3.y = fmaf(s, w3.y, a3.y);
            a3.z = fmaf(s, w3.z, a3.z); a3.w = fmaf(s, w3.w, a3.w);
        }
        pri[k][0]  = a0.x; pri[k][1]  = a0.y; pri[k][2]  = a0.z; pri[k][3]  = a0.w;
        pri[k][4]  = a1.x; pri[k][5]  = a1.y; pri[k][6]  = a1.z; pri[k][7]  = a1.w;
        pri[k][8]  = a2.x; pri[k][9]  = a2.y; pri[k][10] = a2.z; pri[k][11] = a2.w;
        pri[k][12] = a3.x; pri[k][13] = a3.y; pri[k][14] = a3.z; pri[k][15] = a3.w;
        logit[k] = 0.f;
    }

    // ---- dynamic routing ----
    float v[DD];                      // squash output (identical across threads)
    #pragma unroll
    for (int it = 0; it < NITER; ++it) {
        // 1) block max of logits (softmax stability)
        float m = fmaxf(fmaxf(logit[0], logit[1]), logit[2]);
        #pragma unroll
        for (int off = 32; off > 0; off >>= 1)
            m = fmaxf(m, __shfl_xor(m, off));
        __syncthreads();
        if (lane == 0) red_m[wid] = m;
        __syncthreads();
        float M = red_m[0];
        #pragma unroll
        for (int w = 1; w < NWAVES; ++w) M = fmaxf(M, red_m[w]);

        // 2) fused reduction of {sum_e, s[0..15]}
        float e[RPT];
        float vals[17];
        vals[0] = 0.f;
        #pragma unroll
        for (int k = 0; k < RPT; ++k) {
            e[k] = __expf(logit[k] - M);
            vals[0] += e[k];
        }
        #pragma unroll
        for (int d = 0; d < DD; ++d) {
            float s = 0.f;
            #pragma unroll
            for (int k = 0; k < RPT; ++k) s = fmaf(e[k], pri[k][d], s);
            vals[d + 1] = s;
        }
        #pragma unroll
        for (int j = 0; j < 17; ++j) {
            #pragma unroll
            for (int off = 32; off > 0; off >>= 1)
                vals[j] += __shfl_xor(vals[j], off);
        }
        __syncthreads();
        if (lane == 0) {
            #pragma unroll
            for (int j = 0; j < 17; ++j) red_s[wid * 17 + j] = vals[j];
        }
        __syncthreads();
        float S = 0.f;
        float sd[DD];
        {
            float t = 0.f;
            #pragma unroll
            for (int w = 0; w < NWAVES; ++w) t += red_s[w * 17 + 0];
            S = t;
        }
        #pragma unroll
        for (int j = 1; j < 17; ++j) {
            float t = 0.f;
            #pragma unroll
            for (int w = 0; w < NWAVES; ++w) t += red_s[w * 17 + j];
            sd[j - 1] = t;
        }

        // 3) squash (redundant per-thread, all identical)
        const float inv = 1.0f / S;
        float sq = 0.f;
        #pragma unroll
        for (int d = 0; d < DD; ++d) {
            const float x = sd[d] * inv;
            v[d] = x;
            sq = fmaf(x, x, sq);
        }
        const float scale = sqrtf(sq) / (1.0f + sq);
        #pragma unroll
        for (int d = 0; d < DD; ++d) v[d] *= scale;

        // 4) logits += priors . outputs   (skip on last iter: doesn't affect output)
        if (it < NITER - 1) {
            #pragma unroll
            for (int k = 0; k < RPT; ++k) {
                float delta = 0.f;
                #pragma unroll
                for (int d = 0; d < DD; ++d)
                    delta = fmaf(pri[k][d], v[d], delta);
                logit[k] += delta;
            }
        }
    }

    if (tid < DD) out[((size_t)b * OO + o) * DD + tid] = v[tid];
}

extern "C" void kernel_launch(void* const* d_in, const int* in_sizes, int n_in,
                              void* d_out, int out_size, void* d_ws, size_t ws_size,
                              hipStream_t stream) {
    const float* inputs = (const float*)d_in[0];
    const float* route_weights = (const float*)d_in[1];
    float* out = (float*)d_out;
    dim3 grid(BB * OO);
    dim3 block(NTHREADS);
    hipLaunchKernelGGL(capsule_kernel, grid, block, 0, stream,
                       inputs, route_weights, out);
}

// Round 2
// 263.003 us; speedup vs baseline: 1.2643x; 1.2643x over previous
//
#include <hip/hip_runtime.h>

// CapsuleOut: B=256, O=10, R=1152, I=8, D=16, 3 routing iterations.
// Two-kernel plan:
//  K1: transpose W [O,R,128] -> WT [O,128,R] in d_ws (coalesced via padded LDS tile)
//  K2: one block per (o, pair-of-b). 384 threads, 3 routes/thread, priors in regs.
//      W loads now coalesced: for fixed (i,d), lanes read consecutive r.

#define BB 256
#define OO 10
#define RR 1152
#define II 8
#define DD 16
#define NITER 3
#define NTHREADS 384
#define RPT 3
#define NWAVES 6
#define NB 2                     // batches per block
#define GRID2 (OO * BB / NB)     // 1280, divisible by 8 for XCD swizzle

// ---------------- K1: W transpose ----------------
#define TR 64
__global__ __launch_bounds__(256) void transpose_w(
    const float* __restrict__ W, float* __restrict__ wt)
{
    __shared__ float tile[TR][129];           // +1 pad: conflict-free transpose read
    const int o  = blockIdx.x / (RR / TR);
    const int r0 = (blockIdx.x % (RR / TR)) * TR;
    const float* src = W + ((size_t)o * RR + r0) * 128;
    for (int idx = threadIdx.x; idx < TR * 128; idx += 256) {
        const int row = idx >> 7, col = idx & 127;
        tile[row][col] = src[idx];            // coalesced read
    }
    __syncthreads();
    float* dst = wt + (size_t)o * 128 * RR + r0;
    for (int idx = threadIdx.x; idx < TR * 128; idx += 256) {
        const int c = idx >> 6;               // 0..127
        const int r = idx & (TR - 1);         // 0..63, fastest -> coalesced write
        dst[(size_t)c * RR + r] = tile[r][c]; // LDS stride 129: conflict-free
    }
}

// ---------------- K2: main capsule kernel (transposed W) ----------------
__global__ __launch_bounds__(NTHREADS, 3) void capsule_wt(
    const float* __restrict__ inp,   // [B,R,I]
    const float* __restrict__ wt,    // [O,128,R]
    float* __restrict__ out)         // [B,O,D]
{
    // bijective XCD swizzle: each XCD gets a contiguous chunk of 160 wgs
    int wg = blockIdx.x;
    wg = (wg & 7) * (GRID2 / 8) + (wg >> 3);
    const int o  = wg / (BB / NB);
    const int b0 = (wg % (BB / NB)) * NB;
    const int tid = threadIdx.x;
    const int lane = tid & 63;
    const int wid = tid >> 6;

    __shared__ float red_m[NB][NWAVES];
    __shared__ float red_s[NB][NWAVES][17];

    // ---- inputs for this thread's 3 routes x NB batches ----
    float in8[NB][RPT][II];
    #pragma unroll
    for (int nb = 0; nb < NB; ++nb) {
        #pragma unroll
        for (int k = 0; k < RPT; ++k) {
            const float4* irow = reinterpret_cast<const float4*>(
                inp + ((size_t)(b0 + nb) * RR + tid + k * NTHREADS) * II);
            const float4 a = irow[0];
            const float4 c = irow[1];
            in8[nb][k][0] = a.x; in8[nb][k][1] = a.y;
            in8[nb][k][2] = a.z; in8[nb][k][3] = a.w;
            in8[nb][k][4] = c.x; in8[nb][k][5] = c.y;
            in8[nb][k][6] = c.z; in8[nb][k][7] = c.w;
        }
    }

    // ---- priors: coalesced scalar loads from WT ----
    float pri[NB][RPT][DD];
    #pragma unroll
    for (int nb = 0; nb < NB; ++nb)
        #pragma unroll
        for (int k = 0; k < RPT; ++k)
            #pragma unroll
            for (int d = 0; d < DD; ++d)
                pri[nb][k][d] = 0.f;

    const float* wto = wt + (size_t)o * 128 * RR + tid;
    #pragma unroll
    for (int i = 0; i < II; ++i) {
        #pragma unroll
        for (int d = 0; d < DD; ++d) {
            const float* p = wto + (size_t)(i * DD + d) * RR;
            #pragma unroll
            for (int k = 0; k < RPT; ++k) {
                const float w = p[k * NTHREADS];    // +0/+1536/+3072 B imm offsets
                #pragma unroll
                for (int nb = 0; nb < NB; ++nb)
                    pri[nb][k][d] = fmaf(w, in8[nb][k][i], pri[nb][k][d]);
            }
        }
    }

    // ---- dynamic routing ----
    float logit[NB][RPT];
    #pragma unroll
    for (int nb = 0; nb < NB; ++nb)
        #pragma unroll
        for (int k = 0; k < RPT; ++k) logit[nb][k] = 0.f;

    float v[NB][DD];
    #pragma unroll
    for (int it = 0; it < NITER; ++it) {
        // 1) block max of logits per batch
        float m[NB];
        #pragma unroll
        for (int nb = 0; nb < NB; ++nb) {
            float t = fmaxf(fmaxf(logit[nb][0], logit[nb][1]), logit[nb][2]);
            #pragma unroll
            for (int off = 32; off > 0; off >>= 1)
                t = fmaxf(t, __shfl_xor(t, off));
            m[nb] = t;
        }
        __syncthreads();
        if (lane == 0) {
            #pragma unroll
            for (int nb = 0; nb < NB; ++nb) red_m[nb][wid] = m[nb];
        }
        __syncthreads();
        float M[NB];
        #pragma unroll
        for (int nb = 0; nb < NB; ++nb) {
            float t = red_m[nb][0];
            #pragma unroll
            for (int w = 1; w < NWAVES; ++w) t = fmaxf(t, red_m[nb][w]);
            M[nb] = t;
        }

        // 2) fused reduction {sum_e, s[0..15]} per batch (vals reused -> low VGPR)
        __syncthreads();   // protect red_s reuse across iterations
        #pragma unroll
        for (int nb = 0; nb < NB; ++nb) {
            const float e0 = __expf(logit[nb][0] - M[nb]);
            const float e1 = __expf(logit[nb][1] - M[nb]);
            const float e2 = __expf(logit[nb][2] - M[nb]);
            float vals[17];
            vals[0] = e0 + e1 + e2;
            #pragma unroll
            for (int d = 0; d < DD; ++d) {
                float s = e0 * pri[nb][0][d];
                s = fmaf(e1, pri[nb][1][d], s);
                s = fmaf(e2, pri[nb][2][d], s);
                vals[d + 1] = s;
            }
            #pragma unroll
            for (int j = 0; j < 17; ++j) {
                #pragma unroll
                for (int off = 32; off > 0; off >>= 1)
                    vals[j] += __shfl_xor(vals[j], off);
            }
            if (lane == 0) {
                #pragma unroll
                for (int j = 0; j < 17; ++j) red_s[nb][wid][j] = vals[j];
            }
        }
        __syncthreads();

        // 3) cross-wave combine + squash (redundant per-thread)
        #pragma unroll
        for (int nb = 0; nb < NB; ++nb) {
            float S = 0.f;
            #pragma unroll
            for (int w = 0; w < NWAVES; ++w) S += red_s[nb][w][0];
            float sd[DD];
            #pragma unroll
            for (int j = 1; j < 17; ++j) {
                float t = 0.f;
                #pragma unroll
                for (int w = 0; w < NWAVES; ++w) t += red_s[nb][w][j];
                sd[j - 1] = t;
            }
            const float inv = 1.0f / S;
            float sq = 0.f;
            #pragma unroll
            for (int d = 0; d < DD; ++d) {
                const float x = sd[d] * inv;
                v[nb][d] = x;
                sq = fmaf(x, x, sq);
            }
            const float scale = sqrtf(sq) / (1.0f + sq);
            #pragma unroll
            for (int d = 0; d < DD; ++d) v[nb][d] *= scale;
        }

        // 4) logits += priors . outputs (skip last iter)
        if (it < NITER - 1) {
            #pragma unroll
            for (int nb = 0; nb < NB; ++nb)
                #pragma unroll
                for (int k = 0; k < RPT; ++k) {
                    float delta = 0.f;
                    #pragma unroll
                    for (int d = 0; d < DD; ++d)
                        delta = fmaf(pri[nb][k][d], v[nb][d], delta);
                    logit[nb][k] += delta;
                }
        }
    }

    if (tid < DD * NB) {
        const int nb = tid >> 4;
        const int d = tid & 15;
        out[((size_t)(b0 + nb) * OO + o) * DD + d] = v[nb][d];
    }
}

// ---------------- fallback (verified round-1 kernel, NB=1, direct W) ----------------
__global__ __launch_bounds__(NTHREADS) void capsule_legacy(
    const float* __restrict__ inp, const float* __restrict__ W,
    float* __restrict__ out)
{
    const int bid = blockIdx.x;
    const int o = bid / BB;
    const int b = bid % BB;
    const int tid = threadIdx.x;
    const int lane = tid & 63;
    const int wid = tid >> 6;

    __shared__ float red_m[NWAVES];
    __shared__ float red_s[NWAVES * 17];

    float pri[RPT][DD];
    float logit[RPT];

    #pragma unroll
    for (int k = 0; k < RPT; ++k) {
        const int r = tid + k * NTHREADS;
        const float4* wrow = reinterpret_cast<const float4*>(
            W + ((size_t)o * RR + r) * (II * DD));
        const float4* irow = reinterpret_cast<const float4*>(
            inp + ((size_t)b * RR + r) * II);
        const float4 ia = irow[0];
        const float4 ib = irow[1];
        const float in8[8] = {ia.x, ia.y, ia.z, ia.w, ib.x, ib.y, ib.z, ib.w};
        float4 a0 = make_float4(0.f, 0.f, 0.f, 0.f);
        float4 a1 = a0, a2 = a0, a3 = a0;
        #pragma unroll
        for (int i = 0; i < II; ++i) {
            const float s = in8[i];
            const float4 w0 = wrow[i * 4 + 0];
            const float4 w1 = wrow[i * 4 + 1];
            const float4 w2 = wrow[i * 4 + 2];
            const float4 w3 = wrow[i * 4 + 3];
            a0.x = fmaf(s, w0.x, a0.x); a0.y = fmaf(s, w0.y, a0.y);
            a0.z = fmaf(s, w0.z, a0.z); a0.w = fmaf(s, w0.w, a0.w);
            a1.x = fmaf(s, w1.x, a1.x); a1.y = fmaf(s, w1.y, a1.y);
            a1.z = fmaf(s, w1.z, a1.z); a1.w = fmaf(s, w1.w, a1.w);
            a2.x = fmaf(s, w2.x, a2.x); a2.y = fmaf(s, w2.y, a2.y);
            a2.z = fmaf(s, w2.z, a2.z); a2.w = fmaf(s, w2.w, a2.w);
            a3.x = fmaf(s, w3.x, a3.x); a3.y = fmaf(s, w3.y, a3.y);
            a3.z = fmaf(s, w3.z, a3.z); a3.w = fmaf(s, w3.w, a3.w);
        }
        pri[k][0]  = a0.x; pri[k][1]  = a0.y; pri[k][2]  = a0.z; pri[k][3]  = a0.w;
        pri[k][4]  = a1.x; pri[k][5]  = a1.y; pri[k][6]  = a1.z; pri[k][7]  = a1.w;
        pri[k][8]  = a2.x; pri[k][9]  = a2.y; pri[k][10] = a2.z; pri[k][11] = a2.w;
        pri[k][12] = a3.x; pri[k][13] = a3.y; pri[k][14] = a3.z; pri[k][15] = a3.w;
        logit[k] = 0.f;
    }

    float v[DD];
    #pragma unroll
    for (int it = 0; it < NITER; ++it) {
        float m = fmaxf(fmaxf(logit[0], logit[1]), logit[2]);
        #pragma unroll
        for (int off = 32; off > 0; off >>= 1)
            m = fmaxf(m, __shfl_xor(m, off));
        __syncthreads();
        if (lane == 0) red_m[wid] = m;
        __syncthreads();
        float M = red_m[0];
        #pragma unroll
        for (int w = 1; w < NWAVES; ++w) M = fmaxf(M, red_m[w]);

        float e[RPT];
        float vals[17];
        vals[0] = 0.f;
        #pragma unroll
        for (int k = 0; k < RPT; ++k) {
            e[k] = __expf(logit[k] - M);
            vals[0] += e[k];
        }
        #pragma unroll
        for (int d = 0; d < DD; ++d) {
            float s = 0.f;
            #pragma unroll
            for (int k = 0; k < RPT; ++k) s = fmaf(e[k], pri[k][d], s);
            vals[d + 1] = s;
        }
        #pragma unroll
        for (int j = 0; j < 17; ++j) {
            #pragma unroll
            for (int off = 32; off > 0; off >>= 1)
                vals[j] += __shfl_xor(vals[j], off);
        }
        __syncthreads();
        if (lane == 0) {
            #pragma unroll
            for (int j = 0; j < 17; ++j) red_s[wid * 17 + j] = vals[j];
        }
        __syncthreads();
        float S = 0.f;
        float sd[DD];
        {
            float t = 0.f;
            #pragma unroll
            for (int w = 0; w < NWAVES; ++w) t += red_s[w * 17 + 0];
            S = t;
        }
        #pragma unroll
        for (int j = 1; j < 17; ++j) {
            float t = 0.f;
            #pragma unroll
            for (int w = 0; w < NWAVES; ++w) t += red_s[w * 17 + j];
            sd[j - 1] = t;
        }

        const float inv = 1.0f / S;
        float sq = 0.f;
        #pragma unroll
        for (int d = 0; d < DD; ++d) {
            const float x = sd[d] * inv;
            v[d] = x;
            sq = fmaf(x, x, sq);
        }
        const float scale = sqrtf(sq) / (1.0f + sq);
        #pragma unroll
        for (int d = 0; d < DD; ++d) v[d] *= scale;

        if (it < NITER - 1) {
            #pragma unroll
            for (int k = 0; k < RPT; ++k) {
                float delta = 0.f;
                #pragma unroll
                for (int d = 0; d < DD; ++d)
                    delta = fmaf(pri[k][d], v[d], delta);
                logit[k] += delta;
            }
        }
    }

    if (tid < DD) out[((size_t)b * OO + o) * DD + tid] = v[tid];
}

extern "C" void kernel_launch(void* const* d_in, const int* in_sizes, int n_in,
                              void* d_out, int out_size, void* d_ws, size_t ws_size,
                              hipStream_t stream) {
    const float* inputs = (const float*)d_in[0];
    const float* W = (const float*)d_in[1];
    float* out = (float*)d_out;
    const size_t wt_bytes = (size_t)OO * RR * II * DD * sizeof(float);  // 5.9 MB

    if (ws_size >= wt_bytes) {
        float* wt = (float*)d_ws;
        hipLaunchKernelGGL(transpose_w, dim3(OO * (RR / TR)), dim3(256), 0, stream, W, wt);
        hipLaunchKernelGGL(capsule_wt, dim3(GRID2), dim3(NTHREADS), 0, stream, inputs, wt, out);
    } else {
        hipLaunchKernelGGL(capsule_legacy, dim3(BB * OO), dim3(NTHREADS), 0, stream, inputs, W, out);
    }
}

// Round 3
// 140.745 us; speedup vs baseline: 2.3626x; 1.8686x over previous
//
#include <hip/hip_runtime.h>

// CapsuleOut: B=256, O=10, R=1152, I=8, D=16, 3 routing iterations.
//  K1: pack W [O,R,128] -> WT2 [O, 32 panels (i*4+dg), R, float4(d%4)] in d_ws.
//      Main-kernel W loads become fully coalesced b128 (lane r, 16B each).
//  K2: one block per (o, pair-of-b). 384 threads, 3 routes/thread.
//      Batch-0 priors in registers (48 f), batch-1 priors in LDS (73.7 KB, f4).
//      Softmax WITHOUT max-subtraction (logits bounded ~+-30, fp32-safe).
//      Block reduction: 4 DPP-fused VALU stages (16-lane groups) + one b128
//      group write + 34-thread cross-group pass + broadcast reads.

#define BB 256
#define OO 10
#define RR 1152
#define II 8
#define DD 16
#define NITER 3
#define NT 384
#define RPT 3
#define NB 2
#define GRID2 (OO * BB / NB)     // 1280, divisible by 8
#define NGRP (NT / 16)           // 24 sixteen-lane groups

// ---- 16-lane in-register reduction: VALU-pipe only (DPP) ----
template<int CTRL>
__device__ __forceinline__ float dpp_add(float x) {
    int p = __builtin_amdgcn_update_dpp(0, __float_as_int(x), CTRL, 0xF, 0xF, true);
    return x + __int_as_float(p);
}
__device__ __forceinline__ float red16(float x) {
    x = dpp_add<0xB1>(x);    // quad_perm(1,0,3,2)  : xor 1
    x = dpp_add<0x4E>(x);    // quad_perm(2,3,0,1)  : xor 2
    x = dpp_add<0x124>(x);   // row_ror:4
    x = dpp_add<0x128>(x);   // row_ror:8
    return x;                // every lane now holds its 16-lane-group sum
}

// ---------------- K1: pack W into float4 panels ----------------
__global__ __launch_bounds__(256) void transpose_w2(
    const float* __restrict__ W, float4* __restrict__ wt2)
{
    __shared__ float tile[64][129];
    const int o  = blockIdx.x / (RR / 64);
    const int r0 = (blockIdx.x % (RR / 64)) * 64;
    const float* src = W + ((size_t)o * RR + r0) * 128;
    for (int idx = threadIdx.x; idx < 64 * 128; idx += 256)
        tile[idx >> 7][idx & 127] = src[idx];          // coalesced read
    __syncthreads();
    const int r = threadIdx.x & 63;
    for (int c4 = threadIdx.x >> 6; c4 < 32; c4 += 4) {
        float4 v;
        v.x = tile[r][c4 * 4 + 0];
        v.y = tile[r][c4 * 4 + 1];
        v.z = tile[r][c4 * 4 + 2];
        v.w = tile[r][c4 * 4 + 3];
        wt2[((size_t)o * 32 + c4) * RR + r0 + r] = v;  // coalesced 1KB stores
    }
}

// ---------------- K2: main capsule kernel ----------------
__global__ __launch_bounds__(NT, 3) void capsule_main(
    const float* __restrict__ inp,    // [B,R,8]
    const float4* __restrict__ wt2,   // [O,32,R] of float4
    float* __restrict__ out)          // [B,O,16]
{
    __shared__ float4 priB[12 * NT];          // batch-1 priors, 73728 B
    __shared__ float4 red4[2][NGRP][4];       // per-group s[d] partials
    __shared__ float  redS[2][NGRP];          // per-group sum(exp)
    __shared__ float  finalv[2][20];          // final {s[0..15], S}, 16B-aligned rows

    int wg = blockIdx.x;
    wg = (wg & 7) * (GRID2 / 8) + (wg >> 3);  // bijective XCD swizzle
    const int o  = wg / (BB / NB);
    const int b0 = (wg % (BB / NB)) * NB;
    const int tid = threadIdx.x;
    const int g = tid >> 4;                   // 16-lane group id (0..23)
    const int c = tid & 15;

    const float4* w4 = wt2 + (size_t)o * 32 * RR + tid;
    const float4* ip = reinterpret_cast<const float4*>(inp);

    // ---- priors: k-outer keeps live state ~115 VGPRs ----
    float4 p0[RPT][4];                        // batch-0 priors (48 floats)
    #pragma unroll
    for (int k = 0; k < RPT; ++k) {
        const size_t r = (size_t)(tid + k * NT);
        const float4 A0 = ip[((size_t)b0 * RR + r) * 2];
        const float4 A1 = ip[((size_t)b0 * RR + r) * 2 + 1];
        const float4 B0 = ip[((size_t)(b0 + 1) * RR + r) * 2];
        const float4 B1 = ip[((size_t)(b0 + 1) * RR + r) * 2 + 1];
        const float ain[8] = {A0.x, A0.y, A0.z, A0.w, A1.x, A1.y, A1.z, A1.w};
        const float bin[8] = {B0.x, B0.y, B0.z, B0.w, B1.x, B1.y, B1.z, B1.w};
        #pragma unroll
        for (int dg = 0; dg < 4; ++dg) {
            float4 a = make_float4(0.f, 0.f, 0.f, 0.f);
            float4 b = make_float4(0.f, 0.f, 0.f, 0.f);
            #pragma unroll
            for (int i = 0; i < II; ++i) {
                const float4 w = w4[(size_t)(i * 4 + dg) * RR + k * NT]; // b128, coalesced
                a.x = fmaf(w.x, ain[i], a.x); a.y = fmaf(w.y, ain[i], a.y);
                a.z = fmaf(w.z, ain[i], a.z); a.w = fmaf(w.w, ain[i], a.w);
                b.x = fmaf(w.x, bin[i], b.x); b.y = fmaf(w.y, bin[i], b.y);
                b.z = fmaf(w.z, bin[i], b.z); b.w = fmaf(w.w, bin[i], b.w);
            }
            p0[k][dg] = a;
            priB[(k * 4 + dg) * NT + tid] = b;   // thread-private slot, no sync needed
        }
    }

    float lg0[RPT] = {0.f, 0.f, 0.f};
    float lg1[RPT] = {0.f, 0.f, 0.f};

    #pragma unroll
    for (int it = 0; it < NITER; ++it) {
        // ---- batch 0 partials (registers) ----
        {
            const float e0 = __expf(lg0[0]), e1 = __expf(lg0[1]), e2 = __expf(lg0[2]);
            const float S = red16(e0 + e1 + e2);
            float4 s[4];
            #pragma unroll
            for (int dg = 0; dg < 4; ++dg) {
                float4 t;
                t.x = fmaf(e0, p0[0][dg].x, fmaf(e1, p0[1][dg].x, e2 * p0[2][dg].x));
                t.y = fmaf(e0, p0[0][dg].y, fmaf(e1, p0[1][dg].y, e2 * p0[2][dg].y));
                t.z = fmaf(e0, p0[0][dg].z, fmaf(e1, p0[1][dg].z, e2 * p0[2][dg].z));
                t.w = fmaf(e0, p0[0][dg].w, fmaf(e1, p0[1][dg].w, e2 * p0[2][dg].w));
                t.x = red16(t.x); t.y = red16(t.y); t.z = red16(t.z); t.w = red16(t.w);
                s[dg] = t;
            }
            if (c < 4) {
                const float4 wv = (c & 2) ? ((c & 1) ? s[3] : s[2])
                                          : ((c & 1) ? s[1] : s[0]);
                red4[0][g][c] = wv;
            } else if (c == 4) {
                redS[0][g] = S;
            }
        }
        // ---- batch 1 partials (priors from LDS) ----
        {
            const float e0 = __expf(lg1[0]), e1 = __expf(lg1[1]), e2 = __expf(lg1[2]);
            const float S = red16(e0 + e1 + e2);
            float4 s[4];
            #pragma unroll
            for (int dg = 0; dg < 4; ++dg) {
                const float4 q0 = priB[(0 + dg) * NT + tid];
                const float4 q1 = priB[(4 + dg) * NT + tid];
                const float4 q2 = priB[(8 + dg) * NT + tid];
                float4 t;
                t.x = fmaf(e0, q0.x, fmaf(e1, q1.x, e2 * q2.x));
                t.y = fmaf(e0, q0.y, fmaf(e1, q1.y, e2 * q2.y));
                t.z = fmaf(e0, q0.z, fmaf(e1, q1.z, e2 * q2.z));
                t.w = fmaf(e0, q0.w, fmaf(e1, q1.w, e2 * q2.w));
                t.x = red16(t.x); t.y = red16(t.y); t.z = red16(t.z); t.w = red16(t.w);
                s[dg] = t;
            }
            if (c < 4) {
                const float4 wv = (c & 2) ? ((c & 1) ? s[3] : s[2])
                                          : ((c & 1) ? s[1] : s[0]);
                red4[1][g][c] = wv;
            } else if (c == 4) {
                redS[1][g] = S;
            }
        }
        __syncthreads();

        // ---- cross-group reduce: 34 threads, one value each ----
        if (tid < 34) {
            const int nb = (tid >= 17) ? 1 : 0;
            const int j = tid - nb * 17;
            const float* base;
            int stride;
            if (j < 16) { base = (const float*)red4 + nb * (NGRP * 16) + j; stride = 16; }
            else        { base = &redS[nb][0];                              stride = 1;  }
            float t = 0.f;
            #pragma unroll
            for (int gg = 0; gg < NGRP; ++gg) t += base[gg * stride];
            finalv[nb][j] = t;
        }
        __syncthreads();

        // ---- squash + logit update, batch 0 ----
        {
            const float4* fp = reinterpret_cast<const float4*>(&finalv[0][0]);
            const float4 s0 = fp[0], s1 = fp[1], s2 = fp[2], s3 = fp[3];
            const float S = finalv[0][16];
            const float inv = 1.0f / S;
            float sq = 0.f;
            sq = fmaf(s0.x*inv, s0.x*inv, sq); sq = fmaf(s0.y*inv, s0.y*inv, sq);
            sq = fmaf(s0.z*inv, s0.z*inv, sq); sq = fmaf(s0.w*inv, s0.w*inv, sq);
            sq = fmaf(s1.x*inv, s1.x*inv, sq); sq = fmaf(s1.y*inv, s1.y*inv, sq);
            sq = fmaf(s1.z*inv, s1.z*inv, sq); sq = fmaf(s1.w*inv, s1.w*inv, sq);
            sq = fmaf(s2.x*inv, s2.x*inv, sq); sq = fmaf(s2.y*inv, s2.y*inv, sq);
            sq = fmaf(s2.z*inv, s2.z*inv, sq); sq = fmaf(s2.w*inv, s2.w*inv, sq);
            sq = fmaf(s3.x*inv, s3.x*inv, sq); sq = fmaf(s3.y*inv, s3.y*inv, sq);
            sq = fmaf(s3.z*inv, s3.z*inv, sq); sq = fmaf(s3.w*inv, s3.w*inv, sq);
            const float F = inv * sqrtf(sq) / (1.0f + sq);  // v[d] = s[d]*F
            if (it < NITER - 1) {
                #pragma unroll
                for (int k = 0; k < RPT; ++k) {
                    float d = 0.f;
                    d = fmaf(p0[k][0].x, s0.x, d); d = fmaf(p0[k][0].y, s0.y, d);
                    d = fmaf(p0[k][0].z, s0.z, d); d = fmaf(p0[k][0].w, s0.w, d);
                    d = fmaf(p0[k][1].x, s1.x, d); d = fmaf(p0[k][1].y, s1.y, d);
                    d = fmaf(p0[k][1].z, s1.z, d); d = fmaf(p0[k][1].w, s1.w, d);
                    d = fmaf(p0[k][2].x, s2.x, d); d = fmaf(p0[k][2].y, s2.y, d);
                    d = fmaf(p0[k][2].z, s2.z, d); d = fmaf(p0[k][2].w, s2.w, d);
                    d = fmaf(p0[k][3].x, s3.x, d); d = fmaf(p0[k][3].y, s3.y, d);
                    d = fmaf(p0[k][3].z, s3.z, d); d = fmaf(p0[k][3].w, s3.w, d);
                    lg0[k] = fmaf(F, d, lg0[k]);
                }
            } else if (tid < DD) {
                out[((size_t)b0 * OO + o) * DD + tid] = finalv[0][tid] * F;
            }
        }
        // ---- squash + logit update, batch 1 ----
        {
            const float4* fp = reinterpret_cast<const float4*>(&finalv[1][0]);
            const float4 s0 = fp[0], s1 = fp[1], s2 = fp[2], s3 = fp[3];
            const float S = finalv[1][16];
            const float inv = 1.0f / S;
            float sq = 0.f;
            sq = fmaf(s0.x*inv, s0.x*inv, sq); sq = fmaf(s0.y*inv, s0.y*inv, sq);
            sq = fmaf(s0.z*inv, s0.z*inv, sq); sq = fmaf(s0.w*inv, s0.w*inv, sq);
            sq = fmaf(s1.x*inv, s1.x*inv, sq); sq = fmaf(s1.y*inv, s1.y*inv, sq);
            sq = fmaf(s1.z*inv, s1.z*inv, sq); sq = fmaf(s1.w*inv, s1.w*inv, sq);
            sq = fmaf(s2.x*inv, s2.x*inv, sq); sq = fmaf(s2.y*inv, s2.y*inv, sq);
            sq = fmaf(s2.z*inv, s2.z*inv, sq); sq = fmaf(s2.w*inv, s2.w*inv, sq);
            sq = fmaf(s3.x*inv, s3.x*inv, sq); sq = fmaf(s3.y*inv, s3.y*inv, sq);
            sq = fmaf(s3.z*inv, s3.z*inv, sq); sq = fmaf(s3.w*inv, s3.w*inv, sq);
            const float F = inv * sqrtf(sq) / (1.0f + sq);
            if (it < NITER - 1) {
                #pragma unroll
                for (int k = 0; k < RPT; ++k) {
                    float d = 0.f;
                    #pragma unroll
                    for (int dg = 0; dg < 4; ++dg) {
                        const float4 q = priB[(k * 4 + dg) * NT + tid];
                        const float4 sv = (dg == 0) ? s0 : (dg == 1) ? s1 : (dg == 2) ? s2 : s3;
                        d = fmaf(q.x, sv.x, d); d = fmaf(q.y, sv.y, d);
                        d = fmaf(q.z, sv.z, d); d = fmaf(q.w, sv.w, d);
                    }
                    lg1[k] = fmaf(F, d, lg1[k]);
                }
            } else if (tid < DD) {
                out[((size_t)(b0 + 1) * OO + o) * DD + tid] = finalv[1][tid] * F;
            }
        }
    }
}

// ---------------- fallback (round-1 verified, direct W) ----------------
__global__ __launch_bounds__(NT) void capsule_legacy(
    const float* __restrict__ inp, const float* __restrict__ W,
    float* __restrict__ out)
{
    const int bid = blockIdx.x;
    const int o = bid / BB;
    const int b = bid % BB;
    const int tid = threadIdx.x;
    const int lane = tid & 63;
    const int wid = tid >> 6;
    __shared__ float red_m[6];
    __shared__ float red_s[6 * 17];
    float pri[RPT][DD];
    float logit[RPT];
    #pragma unroll
    for (int k = 0; k < RPT; ++k) {
        const int r = tid + k * NT;
        const float4* wrow = reinterpret_cast<const float4*>(W + ((size_t)o * RR + r) * 128);
        const float4* irow = reinterpret_cast<const float4*>(inp + ((size_t)b * RR + r) * II);
        const float4 ia = irow[0];
        const float4 ib = irow[1];
        const float in8[8] = {ia.x, ia.y, ia.z, ia.w, ib.x, ib.y, ib.z, ib.w};
        float4 a0 = make_float4(0.f, 0.f, 0.f, 0.f);
        float4 a1 = a0, a2 = a0, a3 = a0;
        #pragma unroll
        for (int i = 0; i < II; ++i) {
            const float s = in8[i];
            const float4 w0 = wrow[i * 4 + 0];
            const float4 w1 = wrow[i * 4 + 1];
            const float4 w2 = wrow[i * 4 + 2];
            const float4 w3 = wrow[i * 4 + 3];
            a0.x = fmaf(s, w0.x, a0.x); a0.y = fmaf(s, w0.y, a0.y);
            a0.z = fmaf(s, w0.z, a0.z); a0.w = fmaf(s, w0.w, a0.w);
            a1.x = fmaf(s, w1.x, a1.x); a1.y = fmaf(s, w1.y, a1.y);
            a1.z = fmaf(s, w1.z, a1.z); a1.w = fmaf(s, w1.w, a1.w);
            a2.x = fmaf(s, w2.x, a2.x); a2.y = fmaf(s, w2.y, a2.y);
            a2.z = fmaf(s, w2.z, a2.z); a2.w = fmaf(s, w2.w, a2.w);
            a3.x = fmaf(s, w3.x, a3.x); a3.y = fmaf(s, w3.y, a3.y);
            a3.z = fmaf(s, w3.z, a3.z); a3.w = fmaf(s, w3.w, a3.w);
        }
        pri[k][0]  = a0.x; pri[k][1]  = a0.y; pri[k][2]  = a0.z; pri[k][3]  = a0.w;
        pri[k][4]  = a1.x; pri[k][5]  = a1.y; pri[k][6]  = a1.z; pri[k][7]  = a1.w;
        pri[k][8]  = a2.x; pri[k][9]  = a2.y; pri[k][10] = a2.z; pri[k][11] = a2.w;
        pri[k][12] = a3.x; pri[k][13] = a3.y; pri[k][14] = a3.z; pri[k][15] = a3.w;
        logit[k] = 0.f;
    }
    float v[DD];
    #pragma unroll
    for (int it = 0; it < NITER; ++it) {
        float m = fmaxf(fmaxf(logit[0], logit[1]), logit[2]);
        #pragma unroll
        for (int off = 32; off > 0; off >>= 1) m = fmaxf(m, __shfl_xor(m, off));
        __syncthreads();
        if (lane == 0) red_m[wid] = m;
        __syncthreads();
        float M = red_m[0];
        #pragma unroll
        for (int w = 1; w < 6; ++w) M = fmaxf(M, red_m[w]);
        float e[RPT];
        float vals[17];
        vals[0] = 0.f;
        #pragma unroll
        for (int k = 0; k < RPT; ++k) { e[k] = __expf(logit[k] - M); vals[0] += e[k]; }
        #pragma unroll
        for (int d = 0; d < DD; ++d) {
            float s = 0.f;
            #pragma unroll
            for (int k = 0; k < RPT; ++k) s = fmaf(e[k], pri[k][d], s);
            vals[d + 1] = s;
        }
        #pragma unroll
        for (int j = 0; j < 17; ++j) {
            #pragma unroll
            for (int off = 32; off > 0; off >>= 1) vals[j] += __shfl_xor(vals[j], off);
        }
        __syncthreads();
        if (lane == 0) {
            #pragma unroll
            for (int j = 0; j < 17; ++j) red_s[wid * 17 + j] = vals[j];
        }
        __syncthreads();
        float S = 0.f;
        float sd[DD];
        {
            float t = 0.f;
            #pragma unroll
            for (int w = 0; w < 6; ++w) t += red_s[w * 17];
            S = t;
        }
        #pragma unroll
        for (int j = 1; j < 17; ++j) {
            float t = 0.f;
            #pragma unroll
            for (int w = 0; w < 6; ++w) t += red_s[w * 17 + j];
            sd[j - 1] = t;
        }
        const float inv = 1.0f / S;
        float sq = 0.f;
        #pragma unroll
        for (int d = 0; d < DD; ++d) { const float x = sd[d] * inv; v[d] = x; sq = fmaf(x, x, sq); }
        const float scale = sqrtf(sq) / (1.0f + sq);
        #pragma unroll
        for (int d = 0; d < DD; ++d) v[d] *= scale;
        if (it < NITER - 1) {
            #pragma unroll
            for (int k = 0; k < RPT; ++k) {
                float delta = 0.f;
                #pragma unroll
                for (int d = 0; d < DD; ++d) delta = fmaf(pri[k][d], v[d], delta);
                logit[k] += delta;
            }
        }
    }
    if (tid < DD) out[((size_t)b * OO + o) * DD + tid] = v[tid];
}

extern "C" void kernel_launch(void* const* d_in, const int* in_sizes, int n_in,
                              void* d_out, int out_size, void* d_ws, size_t ws_size,
                              hipStream_t stream) {
    const float* inputs = (const float*)d_in[0];
    const float* W = (const float*)d_in[1];
    float* out = (float*)d_out;
    const size_t wt_bytes = (size_t)OO * RR * II * DD * sizeof(float);  // 5.9 MB

    if (ws_size >= wt_bytes) {
        float4* wt2 = (float4*)d_ws;
        hipLaunchKernelGGL(transpose_w2, dim3(OO * (RR / 64)), dim3(256), 0, stream, W, wt2);
        hipLaunchKernelGGL(capsule_main, dim3(GRID2), dim3(NT), 0, stream, inputs, wt2, out);
    } else {
        hipLaunchKernelGGL(capsule_legacy, dim3(BB * OO), dim3(NT), 0, stream, inputs, W, out);
    }
}